// Round 19
// baseline (715.032 us; speedup 1.0000x reference)
//
#include <hip/hip_runtime.h>
#include <cstdio>
#include <cstdint>

// ---------------------------------------------------------------------------
// WindowAttention split pipeline, round 19 (= round 18 with 16-wave GEMM
// blocks: 1024 threads, 4 waves/SIMD, wave tile 32 x 96):
//   prep: wswz32(Wqkv) + wswz32(Wproj) + mask_bits in ONE kernel.
//   gemm_32<NR,MODE>: A (128 rows x full K=384) persistent LDS frag-major
//   (96 KB), staged once, ONE barrier. B direct from global frag-major,
//   2-buffer register rotation. 16 waves = 4M x 4N, acc[1][3] f32x16.
//   MODE 0: A = fp32 x, fused cvt staging (conflict-free chunk map).
//   MODE 1: A = bf16 via global_load_lds; fp32 out.
//   attn: 1 wave/(b,h), planar QKV, bitmask softmax (unchanged).
// Rationale: gemm1 K-loop latency-bound at 2 waves/SIMD (MfmaUtil 21%);
// LDS forbids >1 block/CU, so double waves INSIDE the block instead
// (r10's smaller-block route thrashed L2; this one keeps M=128 geometry).
// Spill tripwire: VGPR=128 + FETCH/WRITE inflation.
// ---------------------------------------------------------------------------

typedef __attribute__((ext_vector_type(8))) short bfrag8;    // 8 bf16 (4 VGPR)
typedef __attribute__((ext_vector_type(4))) float facc4;     // 16x16 acc
typedef __attribute__((ext_vector_type(16))) float facc16;   // 32x32 acc

#define SCALE_Q 0.17677669529663687f
#define PLANE 6422528ull  // 200704 * 32 elems per (t,h) plane

__device__ __forceinline__ unsigned short f2bf(float f) {  // fp32->bf16 RNE
  unsigned int x = __float_as_uint(f);
  x += 0x7fffu + ((x >> 16) & 1u);
  return (unsigned short)(x >> 16);
}

__device__ __forceinline__ void gload_lds16(const void* g, void* l) {
  __builtin_amdgcn_global_load_lds(
      (const __attribute__((address_space(1))) unsigned int*)g,
      (__attribute__((address_space(3))) unsigned int*)l,
      16, 0, 0);
}

// ---- merged prep: weights -> bf16 frag-major (32x32x16) + mask bitmasks ---
// wswz32: fid = (col/32)*24 + k/16; lane lc: col=(fid/24)*32+(lc&31),
// k=(fid%24)*16+(lc>>5)*8; 512 shorts per frag.
__global__ void __launch_bounds__(256) prep_kernel(
    const float* __restrict__ wq, const float* __restrict__ wp,
    const float* __restrict__ mask,
    unsigned short* __restrict__ Bfq, unsigned short* __restrict__ Bfp,
    unsigned long long* __restrict__ bits) {
  const int blk = blockIdx.x;
  if (blk < 288) {
    const float* w = (blk < 216) ? wq : wp;
    unsigned short* Bf = (blk < 216) ? Bfq : Bfp;
    const int t = ((blk < 216) ? blk : blk - 216) * 256 + threadIdx.x;
    const int fid = t >> 6, lc = t & 63;
    const int cg = fid / 24, ksl = fid - cg * 24;
    const int col = cg * 32 + (lc & 31);
    const int k = ksl * 16 + (lc >> 5) * 8;
    const float* src = w + (size_t)col * 384 + k;
    unsigned short* dst = Bf + ((size_t)fid << 9) + (lc << 3);
#pragma unroll
    for (int j = 0; j < 8; ++j) dst[j] = f2bf(src[j]);
  } else {
    const int idx = (blk - 288) * 256 + threadIdx.x;  // 0..4095
    const int wdw = idx >> 6, m = idx & 63;
    unsigned long long bm = 0ull;
    if (m < 49) {
      const float* mp = mask + (size_t)wdw * 2401 + (size_t)m * 49;
      for (int n = 0; n < 49; ++n)
        if (mp[n] > -50.f) bm |= (1ull << n);
    }
    bits[idx] = bm;
  }
}

// ---------------------------------------------------------------------------
// gemm_32: C = A * B^T (+bias). 32x32x16 MFMA, 16 waves = 4M x 4N,
// wave tile 32 x 96, acc[1][3] f32x16, 2-buffer B register rotation.
// A-frag fid = (row/32)*24 + kslot; lane: row=rg*32+(l&31), k=ksl*16+(l>>5)*8.
// C/D map (verified): col = lane&31, row = (r&3) + 8*(r>>2) + 4*(lane>>5).
// ---------------------------------------------------------------------------
#define LB32(dst, ks_)                                                         \
  {                                                                            \
    _Pragma("unroll") for (int ni = 0; ni < 3; ++ni)                           \
        dst[ni] = *(const bfrag8*)(                                            \
            Bf + ((size_t)((cg0 + ni) * 24 + (ks_)) << 9) + (lane << 3));      \
  }

#define MF32(bb, ks_)                                                          \
  {                                                                            \
    const bfrag8 af0 = *(const bfrag8*)(Ab + ((size_t)(ks_) << 10));           \
    _Pragma("unroll") for (int ni = 0; ni < 3; ++ni)                           \
      acc[ni] = __builtin_amdgcn_mfma_f32_32x32x16_bf16(af0, bb[ni],           \
                                                        acc[ni], 0, 0, 0);     \
  }

template <int NR, int MODE, int SWZ>
__global__ void __launch_bounds__(1024, 1) gemm_32(
    const float* __restrict__ Af32, const unsigned short* __restrict__ Abf,
    const unsigned short* __restrict__ Bf, const float* __restrict__ bias,
    unsigned short* __restrict__ qkv, float* __restrict__ f_out) {
  __shared__ __align__(16) unsigned short Alds[128 * 384];  // 96 KB frag-major

  int bid = blockIdx.x;
  bid = (bid & 7) * SWZ + (bid >> 3);      // XCD-contiguous (1568 = 8*196)
  const int tid = threadIdx.x;
  const int lane = tid & 63, w = tid >> 6; // w = 0..15
  const int wr = w >> 2, wc = w & 3;       // 4 M-quarters x 4 N-quarters
  const int l31 = lane & 31, l5 = lane >> 5;
  const size_t a_row0 = (size_t)bid * 128;

  // ---- stage A fragment-major: 6144 chunks of 16B, 6 per thread.
  // chunk c = tid + j*1024: fid = w + j*16 (wave-uniform), lane offset = lane.
  if (MODE == 0) {
#pragma unroll
    for (int j = 0; j < 6; ++j) {
      const int fid = w + j * 16;
      const int rg = fid / 24, ksl = fid - rg * 24;
      const int row = rg * 32 + l31;
      const int k = ksl * 16 + l5 * 8;
      const float* src = Af32 + (a_row0 + row) * 384 + k;
      const float4 v0 = *(const float4*)(src);
      const float4 v1 = *(const float4*)(src + 4);
      bfrag8 h;
      h[0] = (short)f2bf(v0.x); h[1] = (short)f2bf(v0.y);
      h[2] = (short)f2bf(v0.z); h[3] = (short)f2bf(v0.w);
      h[4] = (short)f2bf(v1.x); h[5] = (short)f2bf(v1.y);
      h[6] = (short)f2bf(v1.z); h[7] = (short)f2bf(v1.w);
      *(bfrag8*)((char*)Alds + ((w << 10) + (j << 14)) + (lane << 4)) = h;
    }
  } else {
#pragma unroll
    for (int j = 0; j < 6; ++j) {
      const int fid = w + j * 16;
      const int rg = fid / 24, ksl = fid - rg * 24;
      const int row = rg * 32 + l31;
      const int k = ksl * 16 + l5 * 8;
      gload_lds16(Abf + (a_row0 + row) * 384 + k,
                  (char*)Alds + ((w << 10) + (j << 14)));  // wave-uniform base
    }
  }
  __syncthreads();                         // the ONLY barrier

  // af source: fid = wr*24 + ksl
  const char* Ab = (const char*)Alds + ((size_t)(wr * 24) << 10) + (lane << 4);

  for (int rnd = 0; rnd < NR; ++rnd) {
    const int cg0 = (rnd * 4 + wc) * 3;    // first 32-col group of this wave
    facc16 acc[3];
#pragma unroll
    for (int ni = 0; ni < 3; ++ni)
#pragma unroll
      for (int r = 0; r < 16; ++r) acc[ni][r] = 0.f;

    bfrag8 bA[3], bB[3];
    LB32(bA, 0);
    LB32(bB, 1);
#pragma unroll 1   // ROLLED: prevents load hoisting / register blowup
    for (int ks = 0; ks < 24; ks += 2) {
      MF32(bA, ks);
      if (ks + 2 < 24) LB32(bA, ks + 2);
      MF32(bB, ks + 1);
      if (ks + 3 < 24) LB32(bB, ks + 3);
    }

    // ---- epilogue: col = (cg0+ni)*32 + l31, m = a_row0 + wr*32 +
    //      (r&3) + 8*(r>>2) + 4*l5
    if (MODE == 0) {
#pragma unroll
      for (int ni = 0; ni < 3; ++ni) {
        const int j0 = (cg0 + ni) * 32;               // 32-aligned col base
        const int t = j0 / 384;
        const int rj = j0 - t * 384;
        const int h = rj >> 5;
        unsigned short* pl = qkv + (size_t)(t * 12 + h) * PLANE + l31;
        const float bvv = bias[j0 + l31];
        const float sc = (t == 0) ? SCALE_Q : 1.0f;
#pragma unroll
        for (int r = 0; r < 16; ++r) {
          const size_t m = a_row0 + wr * 32 + (r & 3) + 8 * (r >> 2) + 4 * l5;
          pl[m * 32] = f2bf((acc[ni][r] + bvv) * sc);
        }
      }
    } else {
#pragma unroll
      for (int ni = 0; ni < 3; ++ni) {
        const int col = (cg0 + ni) * 32 + l31;
        const float bvv = bias[col];
#pragma unroll
        for (int r = 0; r < 16; ++r) {
          const size_t m = a_row0 + wr * 32 + (r & 3) + 8 * (r >> 2) + 4 * l5;
          f_out[m * 384 + col] = acc[ni][r] + bvv;
        }
      }
    }
  }
}

// ---------------------------------------------------------------------------
// Attention: one wave per (window b, head h). Planar Q/K/V; Q/K frags direct
// from global; V staged to LDS transposed+swizzled; bitmask softmax.
// ---------------------------------------------------------------------------
__global__ void __launch_bounds__(64) attn_kernel(
    const unsigned short* __restrict__ QKV,        // 36 planes
    const unsigned long long* __restrict__ mbits,  // (64, 64)
    unsigned short* __restrict__ Og) {             // (4096*49, 384) bf16
  __shared__ unsigned short Vt[32 * 64];   // [d][n], byte-XOR swizzled
  __shared__ unsigned short Ps[64 * 64];   // [m][n], byte-XOR swizzled

  const int bid = blockIdx.x;
  const int b = bid / 12, h = bid - b * 12;
  const int lane = threadIdx.x;
  const int l15 = lane & 15, l4 = lane >> 4;

  const bfrag8 z8 = {0, 0, 0, 0, 0, 0, 0, 0};
  const facc4 fz = {0.f, 0.f, 0.f, 0.f};

  const size_t wb = (size_t)b * 49 * 32;
  const unsigned short* Qp = QKV + (size_t)h * PLANE + wb;
  const unsigned short* Kp = QKV + (size_t)(12 + h) * PLANE + wb;
  const unsigned short* Vp = QKV + (size_t)(24 + h) * PLANE + wb;

  // zero ALL of Vt (4096 B): pad cols n in [49,64) must be 0
#pragma unroll
  for (int i = 0; i < 4; ++i)
    *(bfrag8*)((char*)Vt + (lane + i * 64) * 16) = z8;

  // stage V -> Vt transposed (196 real 16B chunks)
#pragma unroll
  for (int i = 0; i < 4; ++i) {
    const int c = lane + i * 64;
    if (c < 196) {
      const bfrag8 vv = *(const bfrag8*)(Vp + c * 8);
      const int n = c >> 2, cc = c & 3;
      const int d0 = cc * 8;
#pragma unroll
      for (int jj = 0; jj < 8; ++jj) {
        const int d = d0 + jj;
        *(unsigned short*)((char*)Vt + (((d << 7) + (n << 1)) ^ ((d & 7) << 4))) =
            (unsigned short)vv[jj];
      }
    }
  }
  __syncthreads();

  // S = Q K^T : frags direct from global. frag[row=l15][k=l4*8+j]
  facc4 s[4][4];
  {
    bfrag8 qa[4], kf[4];
#pragma unroll
    for (int mi = 0; mi < 4; ++mi)
      qa[mi] = *(const bfrag8*)((const char*)Qp + (mi * 16 + l15) * 64 + l4 * 16);
#pragma unroll
    for (int ni = 0; ni < 4; ++ni)
      kf[ni] = *(const bfrag8*)((const char*)Kp + (ni * 16 + l15) * 64 + l4 * 16);
#pragma unroll
    for (int mi = 0; mi < 4; ++mi)
#pragma unroll
      for (int ni = 0; ni < 4; ++ni)
        s[mi][ni] = __builtin_amdgcn_mfma_f32_16x16x32_bf16(qa[mi], kf[ni], fz, 0, 0, 0);
  }

  // bitmask softmax. acc layout: n = ni*16 + l15, m = mi*16 + l4*4 + r
  const unsigned long long* mb = mbits + (size_t)(b & 63) * 64;
  float rinv[4][4];
#pragma unroll
  for (int mi = 0; mi < 4; ++mi)
#pragma unroll
    for (int r = 0; r < 4; ++r) {
      const int m = mi * 16 + l4 * 4 + r;
      const unsigned long long mw = mb[m];
      float mx = -1e30f;
      int ok[4];
#pragma unroll
      for (int ni = 0; ni < 4; ++ni) {
        const int n = ni * 16 + l15;
        ok[ni] = (int)((mw >> n) & 1ull);
        const float v = ok[ni] ? s[mi][ni][r] : -1e30f;
        mx = fmaxf(mx, v);
      }
      mx = fmaxf(mx, __shfl_xor(mx, 1));
      mx = fmaxf(mx, __shfl_xor(mx, 2));
      mx = fmaxf(mx, __shfl_xor(mx, 4));
      mx = fmaxf(mx, __shfl_xor(mx, 8));
      float sum = 0.f;
#pragma unroll
      for (int ni = 0; ni < 4; ++ni) {
        const float p = ok[ni] ? __expf(s[mi][ni][r] - mx) : 0.f;
        s[mi][ni][r] = p;
        sum += p;
      }
      sum += __shfl_xor(sum, 1);
      sum += __shfl_xor(sum, 2);
      sum += __shfl_xor(sum, 4);
      sum += __shfl_xor(sum, 8);
      rinv[mi][r] = 1.0f / sum;
#pragma unroll
      for (int ni = 0; ni < 4; ++ni) {
        const int n = ni * 16 + l15;
        *(unsigned short*)((char*)Ps + (((m << 7) + (n << 1)) ^ ((m & 7) << 4))) =
            f2bf(s[mi][ni][r]);
      }
    }
  __syncthreads();

  // O = P V (unnormalized), then scale by 1/rowsum
  facc4 o[4][2];
#pragma unroll
  for (int mi = 0; mi < 4; ++mi)
#pragma unroll
    for (int di = 0; di < 2; ++di) o[mi][di] = fz;
#pragma unroll
  for (int kk = 0; kk < 2; ++kk) {
    bfrag8 pa[4], vb[2];
#pragma unroll
    for (int mi = 0; mi < 4; ++mi) {
      const int row = mi * 16 + l15;
      pa[mi] = *(const bfrag8*)((const char*)Ps +
                                (((row << 7) + kk * 64 + (l4 << 4)) ^ ((row & 7) << 4)));
    }
#pragma unroll
    for (int di = 0; di < 2; ++di) {
      const int row = di * 16 + l15;
      vb[di] = *(const bfrag8*)((const char*)Vt +
                                (((row << 7) + kk * 64 + (l4 << 4)) ^ ((row & 7) << 4)));
    }
#pragma unroll
    for (int mi = 0; mi < 4; ++mi)
#pragma unroll
      for (int di = 0; di < 2; ++di)
        o[mi][di] = __builtin_amdgcn_mfma_f32_16x16x32_bf16(pa[mi], vb[di], o[mi][di], 0, 0, 0);
  }

  unsigned short* op = Og + (size_t)b * 18816 + h * 32;  // (b, n, C)
#pragma unroll
  for (int mi = 0; mi < 4; ++mi)
#pragma unroll
    for (int r = 0; r < 4; ++r) {
      const int m = mi * 16 + l4 * 4 + r;
      if (m < 49) {
        const float rs = rinv[mi][r];
#pragma unroll
        for (int di = 0; di < 2; ++di)
          op[(size_t)m * 384 + di * 16 + l15] = f2bf(o[mi][di][r] * rs);
      }
    }
}

// ---------------------------------------------------------------------------
extern "C" void kernel_launch(void* const* d_in, const int* in_sizes, int n_in,
                              void* d_out, int out_size, void* d_ws, size_t ws_size,
                              hipStream_t stream) {
  const float* x      = (const float*)d_in[0];  // (4096, 49, 384)
  const float* mask   = (const float*)d_in[1];  // (64, 49, 49)
  const float* w_qkv  = (const float*)d_in[2];  // (1152, 384)
  const float* b_qkv  = (const float*)d_in[3];  // (1152,)
  const float* w_proj = (const float*)d_in[4];  // (384, 384)
  const float* b_proj = (const float*)d_in[5];  // (384,)
  float* out = (float*)d_out;

  const size_t E = 77070336ull;  // 200704*384  (3*E = 36 planes)
  unsigned short* wsu   = (unsigned short*)d_ws;
  unsigned short* qkvp  = wsu;            // planar qkv: 3E
  unsigned short* o_ws  = wsu + 3 * E;    // (200704, 384) bf16
  unsigned short* Bfq   = wsu + 4 * E;    // frag-major W_qkv bf16 (442368)
  unsigned short* Bfp   = Bfq + 442368ull;  // frag-major W_proj bf16 (147456)
  unsigned long long* mb = (unsigned long long*)(Bfp + 147456ull);  // 4096 u64
  const size_t need = (4 * E + 442368ull + 147456ull) * 2ull + 4096ull * 8ull;
  if (ws_size < need) {
    fprintf(stderr, "[WindowAttention] ws too small: need=%zu have=%zu\n",
            (size_t)need, ws_size);
    return;
  }

  // prep: 288 blocks wswz32 (Bfq 864 frags, Bfp 288 frags) + 16 blocks mask
  prep_kernel<<<304, 256, 0, stream>>>(w_qkv, w_proj, mask, Bfq, Bfp, mb);

  // QKV projection (fused fp32->bf16 A-stage): 1568 blocks x 1024 threads
  gemm_32<3, 0, 196><<<1568, 1024, 0, stream>>>(x, nullptr, Bfq, b_qkv,
                                                qkvp, nullptr);

  // attention: one wave per (b, h)
  attn_kernel<<<49152, 64, 0, stream>>>(qkvp, mb, o_ws);

  // output projection: 1 round x 4 waves-cols x 96 = 384
  gemm_32<1, 1, 196><<<1568, 1024, 0, stream>>>(nullptr, o_ws, Bfp, b_proj,
                                                nullptr, out);
}

// Round 20
// 654.579 us; speedup vs baseline: 1.0924x; 1.0924x over previous
//
#include <hip/hip_runtime.h>
#include <cstdio>
#include <cstdint>

// ---------------------------------------------------------------------------
// WindowAttention split pipeline, round 20 (= round 18 + software-pipelined
// af LDS reads in the K-loop; round-19 16-wave geometry REVERTED — smaller
// wave tile doubled operand traffic/MFMA, MfmaUtil fell 21->18.5):
//   prep: wswz32(Wqkv) + wswz32(Wproj) + mask_bits in ONE kernel.
//   gemm_32<NR,MODE>: A (128 rows x full K=384) persistent LDS frag-major,
//   staged once, ONE barrier. B direct from global frag-major, 2-buffer
//   register rotation; af fragments prefetched one phase ahead (the ds_read
//   latency was the last unpipelined operand chain). 8 waves = 2M x 4N,
//   wave tile 64 x 96, acc[2][3] f32x16.
//   MODE 0: A = fp32 x, fused cvt staging (conflict-free chunk map).
//   MODE 1: A = bf16 via global_load_lds; fp32 out.
//   attn: 1 wave/(b,h), planar QKV, bitmask softmax (unchanged).
// Spill tripwire: VGPR=128 + FETCH/WRITE inflation.
// ---------------------------------------------------------------------------

typedef __attribute__((ext_vector_type(8))) short bfrag8;    // 8 bf16 (4 VGPR)
typedef __attribute__((ext_vector_type(4))) float facc4;     // 16x16 acc
typedef __attribute__((ext_vector_type(16))) float facc16;   // 32x32 acc

#define SCALE_Q 0.17677669529663687f
#define PLANE 6422528ull  // 200704 * 32 elems per (t,h) plane

__device__ __forceinline__ unsigned short f2bf(float f) {  // fp32->bf16 RNE
  unsigned int x = __float_as_uint(f);
  x += 0x7fffu + ((x >> 16) & 1u);
  return (unsigned short)(x >> 16);
}

__device__ __forceinline__ void gload_lds16(const void* g, void* l) {
  __builtin_amdgcn_global_load_lds(
      (const __attribute__((address_space(1))) unsigned int*)g,
      (__attribute__((address_space(3))) unsigned int*)l,
      16, 0, 0);
}

// ---- merged prep: weights -> bf16 frag-major (32x32x16) + mask bitmasks ---
__global__ void __launch_bounds__(256) prep_kernel(
    const float* __restrict__ wq, const float* __restrict__ wp,
    const float* __restrict__ mask,
    unsigned short* __restrict__ Bfq, unsigned short* __restrict__ Bfp,
    unsigned long long* __restrict__ bits) {
  const int blk = blockIdx.x;
  if (blk < 288) {
    const float* w = (blk < 216) ? wq : wp;
    unsigned short* Bf = (blk < 216) ? Bfq : Bfp;
    const int t = ((blk < 216) ? blk : blk - 216) * 256 + threadIdx.x;
    const int fid = t >> 6, lc = t & 63;
    const int cg = fid / 24, ksl = fid - cg * 24;
    const int col = cg * 32 + (lc & 31);
    const int k = ksl * 16 + (lc >> 5) * 8;
    const float* src = w + (size_t)col * 384 + k;
    unsigned short* dst = Bf + ((size_t)fid << 9) + (lc << 3);
#pragma unroll
    for (int j = 0; j < 8; ++j) dst[j] = f2bf(src[j]);
  } else {
    const int idx = (blk - 288) * 256 + threadIdx.x;  // 0..4095
    const int wdw = idx >> 6, m = idx & 63;
    unsigned long long bm = 0ull;
    if (m < 49) {
      const float* mp = mask + (size_t)wdw * 2401 + (size_t)m * 49;
      for (int n = 0; n < 49; ++n)
        if (mp[n] > -50.f) bm |= (1ull << n);
    }
    bits[idx] = bm;
  }
}

// ---------------------------------------------------------------------------
// gemm_32: C = A * B^T (+bias). 32x32x16 MFMA, wave tile 64 x 96,
// 8 waves = 2M x 4N, acc[2][3] f32x16.
// A-frag fid = (row/32)*24 + kslot; lane: row=rg*32+(l&31), k=ksl*16+(l>>5)*8.
// C/D map (verified): col = lane&31, row = (r&3) + 8*(r>>2) + 4*(lane>>5).
// ---------------------------------------------------------------------------
#define LB32(dst, ks_)                                                         \
  {                                                                            \
    _Pragma("unroll") for (int ni = 0; ni < 3; ++ni)                           \
        dst[ni] = *(const bfrag8*)(                                            \
            Bf + ((size_t)((cg0 + ni) * 24 + (ks_)) << 9) + (lane << 3));      \
  }

#define MFC(bb, a0_, a1_)                                                      \
  {                                                                            \
    _Pragma("unroll") for (int ni = 0; ni < 3; ++ni) {                         \
      acc[0][ni] = __builtin_amdgcn_mfma_f32_32x32x16_bf16(a0_, bb[ni],        \
                                                           acc[0][ni], 0, 0, 0);\
      acc[1][ni] = __builtin_amdgcn_mfma_f32_32x32x16_bf16(a1_, bb[ni],        \
                                                           acc[1][ni], 0, 0, 0);\
    }                                                                          \
  }

template <int NR, int MODE, int SWZ>
__global__ void __launch_bounds__(512, 1) gemm_32(
    const float* __restrict__ Af32, const unsigned short* __restrict__ Abf,
    const unsigned short* __restrict__ Bf, const float* __restrict__ bias,
    unsigned short* __restrict__ qkv, float* __restrict__ f_out) {
  __shared__ __align__(16) unsigned short Alds[128 * 384];  // 96 KB frag-major

  int bid = blockIdx.x;
  bid = (bid & 7) * SWZ + (bid >> 3);      // XCD-contiguous (1568 = 8*196)
  const int tid = threadIdx.x;
  const int lane = tid & 63, w = tid >> 6;
  const int wr = w >> 2, wc = w & 3;       // 2 M-halves x 4 N-quarters
  const int l31 = lane & 31, l5 = lane >> 5;
  const size_t a_row0 = (size_t)bid * 128;

  if (MODE == 0) {
    // fused fp32 -> bf16 staging, conflict-free chunk map (r18):
    // chunk c = tid + j*512, fid = w + j*8 (wave-uniform), write base+lane*16.
#pragma unroll
    for (int j = 0; j < 12; ++j) {
      const int fid = w + j * 8;
      const int rg = fid / 24, ksl = fid - rg * 24;
      const int row = rg * 32 + l31;
      const int k = ksl * 16 + l5 * 8;
      const float* src = Af32 + (a_row0 + row) * 384 + k;
      const float4 v0 = *(const float4*)(src);
      const float4 v1 = *(const float4*)(src + 4);
      bfrag8 h;
      h[0] = (short)f2bf(v0.x); h[1] = (short)f2bf(v0.y);
      h[2] = (short)f2bf(v0.z); h[3] = (short)f2bf(v0.w);
      h[4] = (short)f2bf(v1.x); h[5] = (short)f2bf(v1.y);
      h[6] = (short)f2bf(v1.z); h[7] = (short)f2bf(v1.w);
      *(bfrag8*)((char*)Alds + ((w << 10) + (j << 13)) + (lane << 4)) = h;
    }
  } else {
    // bf16 source: 6144 chunks of 16B via global_load_lds, 12/thread.
#pragma unroll
    for (int j = 0; j < 12; ++j) {
      const int fid = w + j * 8;
      const int rg = fid / 24, ksl = fid - rg * 24;
      const int row = rg * 32 + l31;
      const int k = ksl * 16 + l5 * 8;
      gload_lds16(Abf + (a_row0 + row) * 384 + k,
                  (char*)Alds + ((w << 10) + (j << 13)));  // wave-uniform base
    }
  }
  __syncthreads();                         // the ONLY barrier

  // af source: fid = (wr*2 + mi)*24 + ksl
  const char* Ab = (const char*)Alds + ((size_t)(wr * 48) << 10) + (lane << 4);

  for (int rnd = 0; rnd < NR; ++rnd) {
    const int cg0 = (rnd * 4 + wc) * 3;    // first 32-col group of this wave
    facc16 acc[2][3];
#pragma unroll
    for (int mi = 0; mi < 2; ++mi)
#pragma unroll
      for (int ni = 0; ni < 3; ++ni)
#pragma unroll
        for (int r = 0; r < 16; ++r) acc[mi][ni][r] = 0.f;

    bfrag8 bA[3], bB[3];
    LB32(bA, 0);
    LB32(bB, 1);
    // af pipeline: cur = ksl, nxt = ksl+1 (prefetched one phase ahead)
    bfrag8 a0c = *(const bfrag8*)(Ab);
    bfrag8 a1c = *(const bfrag8*)(Ab + (24 << 10));
#pragma unroll 1   // ROLLED: prevents load hoisting / register blowup
    for (int ks = 0; ks < 24; ks += 2) {
      // prefetch af for phase ks+1
      const bfrag8 a0n = *(const bfrag8*)(Ab + ((size_t)(ks + 1) << 10));
      const bfrag8 a1n = *(const bfrag8*)(Ab + ((size_t)(25 + ks) << 10));
      MFC(bA, a0c, a1c);
      if (ks + 2 < 24) LB32(bA, ks + 2);
      // prefetch af for phase ks+2 (clamped index; extra read is harmless)
      const int ks2 = (ks + 2 < 24) ? (ks + 2) : 23;
      const bfrag8 a0f = *(const bfrag8*)(Ab + ((size_t)ks2 << 10));
      const bfrag8 a1f = *(const bfrag8*)(Ab + ((size_t)(24 + ks2) << 10));
      MFC(bB, a0n, a1n);
      if (ks + 3 < 24) LB32(bB, ks + 3);
      a0c = a0f;
      a1c = a1f;
    }

    // ---- epilogue: col = (cg0+ni)*32 + l31, m = a_row0 + wr*64 + mi*32 +
    //      (r&3) + 8*(r>>2) + 4*l5
    if (MODE == 0) {
#pragma unroll
      for (int ni = 0; ni < 3; ++ni) {
        const int j0 = (cg0 + ni) * 32;               // 32-aligned col base
        const int t = j0 / 384;
        const int rj = j0 - t * 384;
        const int h = rj >> 5;
        unsigned short* pl = qkv + (size_t)(t * 12 + h) * PLANE + l31;
        const float bvv = bias[j0 + l31];
        const float sc = (t == 0) ? SCALE_Q : 1.0f;
#pragma unroll
        for (int mi = 0; mi < 2; ++mi)
#pragma unroll
          for (int r = 0; r < 16; ++r) {
            const size_t m = a_row0 + wr * 64 + mi * 32 +
                             (r & 3) + 8 * (r >> 2) + 4 * l5;
            pl[m * 32] = f2bf((acc[mi][ni][r] + bvv) * sc);
          }
      }
    } else {
#pragma unroll
      for (int ni = 0; ni < 3; ++ni) {
        const int col = (cg0 + ni) * 32 + l31;
        const float bvv = bias[col];
#pragma unroll
        for (int mi = 0; mi < 2; ++mi)
#pragma unroll
          for (int r = 0; r < 16; ++r) {
            const size_t m = a_row0 + wr * 64 + mi * 32 +
                             (r & 3) + 8 * (r >> 2) + 4 * l5;
            f_out[m * 384 + col] = acc[mi][ni][r] + bvv;
          }
      }
    }
  }
}

// ---------------------------------------------------------------------------
// Attention: one wave per (window b, head h). Planar Q/K/V; Q/K frags direct
// from global; V staged to LDS transposed+swizzled; bitmask softmax.
// ---------------------------------------------------------------------------
__global__ void __launch_bounds__(64) attn_kernel(
    const unsigned short* __restrict__ QKV,        // 36 planes
    const unsigned long long* __restrict__ mbits,  // (64, 64)
    unsigned short* __restrict__ Og) {             // (4096*49, 384) bf16
  __shared__ unsigned short Vt[32 * 64];   // [d][n], byte-XOR swizzled
  __shared__ unsigned short Ps[64 * 64];   // [m][n], byte-XOR swizzled

  const int bid = blockIdx.x;
  const int b = bid / 12, h = bid - b * 12;
  const int lane = threadIdx.x;
  const int l15 = lane & 15, l4 = lane >> 4;

  const bfrag8 z8 = {0, 0, 0, 0, 0, 0, 0, 0};
  const facc4 fz = {0.f, 0.f, 0.f, 0.f};

  const size_t wb = (size_t)b * 49 * 32;
  const unsigned short* Qp = QKV + (size_t)h * PLANE + wb;
  const unsigned short* Kp = QKV + (size_t)(12 + h) * PLANE + wb;
  const unsigned short* Vp = QKV + (size_t)(24 + h) * PLANE + wb;

  // zero ALL of Vt (4096 B): pad cols n in [49,64) must be 0
#pragma unroll
  for (int i = 0; i < 4; ++i)
    *(bfrag8*)((char*)Vt + (lane + i * 64) * 16) = z8;

  // stage V -> Vt transposed (196 real 16B chunks)
#pragma unroll
  for (int i = 0; i < 4; ++i) {
    const int c = lane + i * 64;
    if (c < 196) {
      const bfrag8 vv = *(const bfrag8*)(Vp + c * 8);
      const int n = c >> 2, cc = c & 3;
      const int d0 = cc * 8;
#pragma unroll
      for (int jj = 0; jj < 8; ++jj) {
        const int d = d0 + jj;
        *(unsigned short*)((char*)Vt + (((d << 7) + (n << 1)) ^ ((d & 7) << 4))) =
            (unsigned short)vv[jj];
      }
    }
  }
  __syncthreads();

  // S = Q K^T : frags direct from global. frag[row=l15][k=l4*8+j]
  facc4 s[4][4];
  {
    bfrag8 qa[4], kf[4];
#pragma unroll
    for (int mi = 0; mi < 4; ++mi)
      qa[mi] = *(const bfrag8*)((const char*)Qp + (mi * 16 + l15) * 64 + l4 * 16);
#pragma unroll
    for (int ni = 0; ni < 4; ++ni)
      kf[ni] = *(const bfrag8*)((const char*)Kp + (ni * 16 + l15) * 64 + l4 * 16);
#pragma unroll
    for (int mi = 0; mi < 4; ++mi)
#pragma unroll
      for (int ni = 0; ni < 4; ++ni)
        s[mi][ni] = __builtin_amdgcn_mfma_f32_16x16x32_bf16(qa[mi], kf[ni], fz, 0, 0, 0);
  }

  // bitmask softmax. acc layout: n = ni*16 + l15, m = mi*16 + l4*4 + r
  const unsigned long long* mb = mbits + (size_t)(b & 63) * 64;
  float rinv[4][4];
#pragma unroll
  for (int mi = 0; mi < 4; ++mi)
#pragma unroll
    for (int r = 0; r < 4; ++r) {
      const int m = mi * 16 + l4 * 4 + r;
      const unsigned long long mw = mb[m];
      float mx = -1e30f;
      int ok[4];
#pragma unroll
      for (int ni = 0; ni < 4; ++ni) {
        const int n = ni * 16 + l15;
        ok[ni] = (int)((mw >> n) & 1ull);
        const float v = ok[ni] ? s[mi][ni][r] : -1e30f;
        mx = fmaxf(mx, v);
      }
      mx = fmaxf(mx, __shfl_xor(mx, 1));
      mx = fmaxf(mx, __shfl_xor(mx, 2));
      mx = fmaxf(mx, __shfl_xor(mx, 4));
      mx = fmaxf(mx, __shfl_xor(mx, 8));
      float sum = 0.f;
#pragma unroll
      for (int ni = 0; ni < 4; ++ni) {
        const float p = ok[ni] ? __expf(s[mi][ni][r] - mx) : 0.f;
        s[mi][ni][r] = p;
        sum += p;
      }
      sum += __shfl_xor(sum, 1);
      sum += __shfl_xor(sum, 2);
      sum += __shfl_xor(sum, 4);
      sum += __shfl_xor(sum, 8);
      rinv[mi][r] = 1.0f / sum;
#pragma unroll
      for (int ni = 0; ni < 4; ++ni) {
        const int n = ni * 16 + l15;
        *(unsigned short*)((char*)Ps + (((m << 7) + (n << 1)) ^ ((m & 7) << 4))) =
            f2bf(s[mi][ni][r]);
      }
    }
  __syncthreads();

  // O = P V (unnormalized), then scale by 1/rowsum
  facc4 o[4][2];
#pragma unroll
  for (int mi = 0; mi < 4; ++mi)
#pragma unroll
    for (int di = 0; di < 2; ++di) o[mi][di] = fz;
#pragma unroll
  for (int kk = 0; kk < 2; ++kk) {
    bfrag8 pa[4], vb[2];
#pragma unroll
    for (int mi = 0; mi < 4; ++mi) {
      const int row = mi * 16 + l15;
      pa[mi] = *(const bfrag8*)((const char*)Ps +
                                (((row << 7) + kk * 64 + (l4 << 4)) ^ ((row & 7) << 4)));
    }
#pragma unroll
    for (int di = 0; di < 2; ++di) {
      const int row = di * 16 + l15;
      vb[di] = *(const bfrag8*)((const char*)Vt +
                                (((row << 7) + kk * 64 + (l4 << 4)) ^ ((row & 7) << 4)));
    }
#pragma unroll
    for (int mi = 0; mi < 4; ++mi)
#pragma unroll
      for (int di = 0; di < 2; ++di)
        o[mi][di] = __builtin_amdgcn_mfma_f32_16x16x32_bf16(pa[mi], vb[di], o[mi][di], 0, 0, 0);
  }

  unsigned short* op = Og + (size_t)b * 18816 + h * 32;  // (b, n, C)
#pragma unroll
  for (int mi = 0; mi < 4; ++mi)
#pragma unroll
    for (int r = 0; r < 4; ++r) {
      const int m = mi * 16 + l4 * 4 + r;
      if (m < 49) {
        const float rs = rinv[mi][r];
#pragma unroll
        for (int di = 0; di < 2; ++di)
          op[(size_t)m * 384 + di * 16 + l15] = f2bf(o[mi][di][r] * rs);
      }
    }
}

// ---------------------------------------------------------------------------
extern "C" void kernel_launch(void* const* d_in, const int* in_sizes, int n_in,
                              void* d_out, int out_size, void* d_ws, size_t ws_size,
                              hipStream_t stream) {
  const float* x      = (const float*)d_in[0];  // (4096, 49, 384)
  const float* mask   = (const float*)d_in[1];  // (64, 49, 49)
  const float* w_qkv  = (const float*)d_in[2];  // (1152, 384)
  const float* b_qkv  = (const float*)d_in[3];  // (1152,)
  const float* w_proj = (const float*)d_in[4];  // (384, 384)
  const float* b_proj = (const float*)d_in[5];  // (384,)
  float* out = (float*)d_out;

  const size_t E = 77070336ull;  // 200704*384  (3*E = 36 planes)
  unsigned short* wsu   = (unsigned short*)d_ws;
  unsigned short* qkvp  = wsu;            // planar qkv: 3E
  unsigned short* o_ws  = wsu + 3 * E;    // (200704, 384) bf16
  unsigned short* Bfq   = wsu + 4 * E;    // frag-major W_qkv bf16 (442368)
  unsigned short* Bfp   = Bfq + 442368ull;  // frag-major W_proj bf16 (147456)
  unsigned long long* mb = (unsigned long long*)(Bfp + 147456ull);  // 4096 u64
  const size_t need = (4 * E + 442368ull + 147456ull) * 2ull + 4096ull * 8ull;
  if (ws_size < need) {
    fprintf(stderr, "[WindowAttention] ws too small: need=%zu have=%zu\n",
            (size_t)need, ws_size);
    return;
  }

  // prep: 288 blocks wswz32 (Bfq 864 frags, Bfp 288 frags) + 16 blocks mask
  prep_kernel<<<304, 256, 0, stream>>>(w_qkv, w_proj, mask, Bfq, Bfp, mb);

  // QKV projection (fused fp32->bf16 A-stage): 1568 blocks, 3 rounds x 96
  gemm_32<3, 0, 196><<<1568, 512, 0, stream>>>(x, nullptr, Bfq, b_qkv,
                                               qkvp, nullptr);

  // attention: one wave per (b, h)
  attn_kernel<<<49152, 64, 0, stream>>>(qkvp, mb, o_ws);

  // output projection: 1 round x 4 waves x 96 = 384
  gemm_32<1, 1, 196><<<1568, 512, 0, stream>>>(nullptr, o_ws, Bfp, b_proj,
                                               nullptr, out);
}